// Round 5
// baseline (7056.367 us; speedup 1.0000x reference)
//
#include <hip/hip_runtime.h>
#include <math.h>

typedef _Float16 half_t;
typedef _Float16 half8 __attribute__((ext_vector_type(8)));
typedef float f32x4 __attribute__((ext_vector_type(4)));
typedef unsigned long long u64;

#define B_ 128
#define T_ 256
#define I_ 512
#define H_ 1024

#define mfma16 __builtin_amdgcn_mfma_f32_16x16x32_f16

// ---------------------------------------------------------------------------
// prep: convert x fp32 -> fp16, TRANSPOSED to [t][row][k] (per-step slab = 128KB)
__global__ void k_convert_x(const float* __restrict__ x, half_t* __restrict__ x16, int n8) {
    int i = blockIdx.x * blockDim.x + threadIdx.x;
    if (i >= n8) return;
    const float4* xv = (const float4*)x;
    float4 a = xv[2 * i], b = xv[2 * i + 1];
    half8 o;
    o[0] = (half_t)a.x; o[1] = (half_t)a.y; o[2] = (half_t)a.z; o[3] = (half_t)a.w;
    o[4] = (half_t)b.x; o[5] = (half_t)b.y; o[6] = (half_t)b.z; o[7] = (half_t)b.w;
    int e = i * 8;
    int k = e & (I_ - 1);
    int t = (e >> 9) & (T_ - 1);
    int row = e >> 17;
    ((half8*)x16)[(((size_t)t * B_ + row) * I_ + k) >> 3] = o;
}

// prep: pack W_ih|W_hh (fp32, torch gate order i,f,g,o) into fp16 MFMA
// B-fragment order. Layout: [hgroup(128)][kb(Ktot/32)][ntile(2)][lane(64)][j(8)]
__global__ void k_pack_w(const float* __restrict__ Wih, const float* __restrict__ Whh,
                         half_t* __restrict__ out, int Kx, int Ktot) {
    int idx = blockIdx.x * blockDim.x + threadIdx.x;
    int total = 4096 * Ktot;
    if (idx >= total) return;
    int j = idx & 7;
    int lane = (idx >> 3) & 63;
    int nt = (idx >> 9) & 1;
    int rest = idx >> 10;
    int nkb = Ktot >> 5;
    int kb = rest % nkb;
    int hg = rest / nkb;
    int nl = nt * 16 + (lane & 15);
    int gate = nl >> 3, hoff = nl & 7;
    int row = gate * 1024 + hg * 8 + hoff;
    int k = kb * 32 + (lane >> 4) * 8 + j;
    float v = (k < Kx) ? Wih[(size_t)row * Kx + k] : Whh[(size_t)row * 1024 + (k - Kx)];
    out[idx] = (half_t)v;
}

// prep: bias packed to [hgroup*32 + gate*8 + hoff], b_ih + b_hh summed
__global__ void k_pack_bias(const float* __restrict__ bih, const float* __restrict__ bhh,
                            float* __restrict__ out) {
    int idx = blockIdx.x * blockDim.x + threadIdx.x;
    if (idx >= 4096) return;
    int hg = idx >> 5, c = idx & 31;
    int gate = c >> 3, hoff = c & 7;
    int row = gate * 1024 + hg * 8 + hoff;
    out[idx] = bih[row] + bhh[row];
}

__global__ void k_zero(unsigned int* __restrict__ p, int n) {
    int i = blockIdx.x * blockDim.x + threadIdx.x;
    if (i < n) p[i] = 0u;
}

// ---------------------------------------------------------------------------
// system-scope primitives (validated r2-r4: write-through store + fresh-address
// cached load is coherent; sysld for reused addresses)
__device__ __forceinline__ u64 sysld64(const half_t* p) {
    return __hip_atomic_load((const u64*)p, __ATOMIC_RELAXED, __HIP_MEMORY_SCOPE_SYSTEM);
}
__device__ __forceinline__ void sysst32(half_t* p, unsigned v) {
    __hip_atomic_store((unsigned*)p, v, __ATOMIC_RELAXED, __HIP_MEMORY_SCOPE_SYSTEM);
}
union H8U { half8 h; u64 u[2]; };

// Per-wave wait on 16 consecutive flags (one 64B line). No RMW, no fences.
__device__ __forceinline__ void wait_flags16(const unsigned* f, unsigned tgt) {
    int lane = threadIdx.x & 63;
    int gd = 0;
    for (;;) {
        unsigned v = tgt;
        if (lane < 16)
            v = __hip_atomic_load(f + lane, __ATOMIC_RELAXED, __HIP_MEMORY_SCOPE_SYSTEM);
        if (__all((int)(v >= tgt))) break;
        __builtin_amdgcn_s_sleep(2);
        if (++gd > (1 << 14)) break;  // failsafe: visible fail, not a hang
    }
}

// ---------------------------------------------------------------------------
// One layer, persistent. Block = 512 thr = 8 waves. Block tile: 32 rows (rg)
// x 32 gate-cols (cg == hgroup). Weights live in registers, pinned.
// Phase 1: non-recurrent K (x / h1seq[t+1]), kbs NI_X*ks..+NI_X per wave.
// Phase 2: recurrent K, CONTIGUOUS kbs (KX/32 + 4ks..+4) -> wave ks depends
// on h units [128ks,128ks+128) = producer flags cg' in [16ks,16ks+16) only.
// Union over 8 waves = all 128 flags >= t before the block's syncthreads,
// which preserves the old full-barrier WAR safety while overlapping waits.
template <int KX, bool LAY1, bool H2SEQ>
__device__ void run_layer(const half_t* __restrict__ srcX,
                          half_t* hA, half_t* hB,
                          const half_t* __restrict__ Wp, const float* __restrict__ biasp,
                          unsigned* flagsPre, unsigned* flagsOwn,   // [rg*128 + cg]
                          int rg, int cg, float* gacc)
{
    constexpr int KTOT = KX + 1024;
    constexpr int NKB  = KTOT >> 5;   // 48 / 64
    constexpr int NI_X = KX >> 8;     // 2 / 4 phase-1 kbs per wave
    constexpr int NI_H = 4;           // phase-2 kbs per wave
    constexpr int NI   = NI_X + NI_H; // 6 / 8

    const int tid = threadIdx.x;
    const int ks = tid >> 6, lane = tid & 63;
    const int q = lane >> 4, ml = lane & 15;
    const int hg = cg;
    const int r0 = rg * 32;

    // ---- one-time weight preload into registers, pinned (no remat/sink) ----
    half8 Breg[NI][2];
    {
        const half8* Wp8 = (const half8*)Wp;
        size_t base = (size_t)hg * NKB * 128 + lane;
#pragma unroll
        for (int i = 0; i < NI; ++i) {
            int kb = (i < NI_X) ? (NI_X * ks + i) : (KX / 32 + 4 * ks + (i - NI_X));
            Breg[i][0] = Wp8[base + (size_t)kb * 128];
            Breg[i][1] = Wp8[base + (size_t)kb * 128 + 64];
        }
#pragma unroll
        for (int i = 0; i < NI; ++i)
            asm volatile("" : "+v"(Breg[i][0]), "+v"(Breg[i][1]));
    }

    const int erow = tid >> 3, ehoff = tid & 7;  // elementwise id (tid<256)
    float bi = 0.f, bf = 0.f, bgc = 0.f, bo = 0.f;
    if (tid < 256) {
        bi  = biasp[hg * 32 + 0 + ehoff];
        bf  = biasp[hg * 32 + 8 + ehoff];
        bgc = biasp[hg * 32 + 16 + ehoff];
        bo  = biasp[hg * 32 + 24 + ehoff];
    }
    float c_reg = 0.f;

    const unsigned* myPre = flagsPre + rg * 128 + 16 * ks;
    const unsigned* myOwn = flagsOwn + rg * 128 + 16 * ks;
    unsigned* myFlag = flagsOwn + rg * 128 + cg;

    for (int t = 0; t < T_; ++t) {
        f32x4 acc[2][2];
        acc[0][0] = (f32x4)0.f; acc[0][1] = (f32x4)0.f;
        acc[1][0] = (f32x4)0.f; acc[1][1] = (f32x4)0.f;

        // ---- phase 1: non-recurrent operand ----
        if constexpr (LAY1) {
            wait_flags16(myPre, (unsigned)(t + 1));  // h1seq[t+1] slice ready
            asm volatile("" ::: "memory");
        }
        const int t1 = LAY1 ? (t + 1) : t;
#pragma unroll
        for (int i = 0; i < NI_X; ++i) {
            int kg = 32 * (NI_X * ks + i) + q * 8;
#pragma unroll
            for (int rt = 0; rt < 2; ++rt) {
                int grow = r0 + rt * 16 + ml;
                half8 a = *(const half8*)(srcX + ((size_t)t1 * B_ + grow) * KX + kg);
                acc[rt][0] = mfma16(a, Breg[i][0], acc[rt][0], 0, 0, 0);
                acc[rt][1] = mfma16(a, Breg[i][1], acc[rt][1], 0, 0, 0);
            }
        }
        // ---- phase 2: recurrent operand, per-wave fine-grained dependency ----
        if (t > 0) {
            wait_flags16(myOwn, (unsigned)t);
            asm volatile("" ::: "memory");
        }
        const half_t* hp;
        if constexpr (!LAY1 || H2SEQ) hp = hA + (size_t)t * B_ * H_;
        else                          hp = (t & 1) ? hB : hA;
#pragma unroll
        for (int j = 0; j < NI_H; ++j) {
            int i = NI_X + j;
            int kh = 32 * (4 * ks + j) + q * 8;   // h-unit index in [0,1024)
#pragma unroll
            for (int rt = 0; rt < 2; ++rt) {
                int grow = r0 + rt * 16 + ml;
                half8 a;
                if constexpr (LAY1 && !H2SEQ) {
                    H8U u; const half_t* p = hp + (size_t)grow * H_ + kh;
                    u.u[0] = sysld64(p); u.u[1] = sysld64(p + 4);
                    a = u.h;
                } else {
                    a = *(const half8*)(hp + (size_t)grow * H_ + kh);
                }
                acc[rt][0] = mfma16(a, Breg[i][0], acc[rt][0], 0, 0, 0);
                acc[rt][1] = mfma16(a, Breg[i][1], acc[rt][1], 0, 0, 0);
            }
        }
        // ---- partials -> LDS (<=2-way conflicts) ----
#pragma unroll
        for (int rt = 0; rt < 2; ++rt)
#pragma unroll
            for (int ct = 0; ct < 2; ++ct)
#pragma unroll
                for (int r = 0; r < 4; ++r) {
                    int rl = rt * 16 + q * 4 + r;
                    int cl = ct * 16 + ml;
                    gacc[(ks * 32 + rl) * 32 + (cl ^ ((rl & 7) << 2))] = acc[rt][ct][r];
                }
        __syncthreads();
        // ---- reduce 8 K-slices + elementwise (tid<256), c in register ----
        if (tid < 256) {
            int swz = (erow & 7) << 2;
            float pi = 0.f, pf = 0.f, pg = 0.f, po = 0.f;
#pragma unroll
            for (int z = 0; z < 8; ++z) {
                const float* g = &gacc[(z * 32 + erow) * 32];
                pi += g[(0 + ehoff) ^ swz];
                pf += g[(8 + ehoff) ^ swz];
                pg += g[(16 + ehoff) ^ swz];
                po += g[(24 + ehoff) ^ swz];
            }
            pi += bi; pf += bf; pg += bgc; po += bo;
            float si = 1.f / (1.f + __expf(-pi));
            float sf = 1.f / (1.f + __expf(-pf));
            float so = 1.f / (1.f + __expf(-po));
            float tg = 1.f - 2.f / (__expf(2.f * pg) + 1.f);
            c_reg = sf * c_reg + si * tg;
            float th = 1.f - 2.f / (__expf(2.f * c_reg) + 1.f);
            float hn = so * th;
            union { _Float16 hf; unsigned short us; } cvt; cvt.hf = (_Float16)hn;
            unsigned mine = cvt.us;
            unsigned other = (unsigned)__shfl_down((int)mine, 1, 64);
            if ((ehoff & 1) == 0) {  // pack pair -> one u32 write-through store
                unsigned pk = mine | ((other & 0xffffu) << 16);
                int grow = r0 + erow;
                half_t* dst;
                if constexpr (!LAY1 || H2SEQ)
                    dst = hA + ((size_t)(t + 1) * B_ + grow) * H_ + hg * 8 + ehoff;
                else
                    dst = ((t & 1) ? hA : hB) + (size_t)grow * H_ + hg * 8 + ehoff;
                sysst32(dst, pk);
            }
        }
        __syncthreads();  // all waves' h-stores drained (pre-barrier vmcnt(0))
        if (tid == 0)     // publish: single release store, no RMW
            __hip_atomic_store(myFlag, (unsigned)(t + 1),
                               __ATOMIC_RELEASE, __HIP_MEMORY_SCOPE_SYSTEM);
    }
}

// ---------------------------------------------------------------------------
// 512 blocks x 512 thr, 2 blocks/CU. Sequential layers per block, but blocks
// flow into L1 as soon as their fine-grained L0 deps allow (pipelined tail).
// rg = bid&3 keeps each rg-group on a stable XCD subset (locality only).
template <bool H2SEQ>
__launch_bounds__(512, 4)
__global__ void lstm_persist(const half_t* __restrict__ x16T, half_t* h1seq,
                             half_t* h2A, half_t* h2B,
                             const half_t* __restrict__ wp0, const half_t* __restrict__ wp1,
                             const float* __restrict__ bias0, const float* __restrict__ bias1,
                             unsigned* __restrict__ flags0, unsigned* __restrict__ flags1)
{
    __shared__ float gacc[8 * 32 * 32];  // 32 KB
    int bid = blockIdx.x;
    int rg = bid & 3;
    int cg = bid >> 2;

    run_layer<512, false, true>(x16T, h1seq, (half_t*)0, wp0, bias0,
                                flags0, flags0, rg, cg, gacc);
    run_layer<1024, true, H2SEQ>(h1seq, h2A, h2B, wp1, bias1,
                                 flags0, flags1, rg, cg, gacc);
}

// final FC: out[m] = sum_k h[m][k] * Wfc[k] + bfc  (NC=1)
__global__ void k_fc(const half_t* __restrict__ h, const float* __restrict__ Wfc,
                     const float* __restrict__ bfc, float* __restrict__ out) {
    int m = blockIdx.x, lane = threadIdx.x;
    float s = 0.f;
    for (int k = lane; k < H_; k += 64) s += (float)h[m * H_ + k] * Wfc[k];
#pragma unroll
    for (int o = 32; o; o >>= 1) s += __shfl_down(s, o, 64);
    if (lane == 0) out[m] = s + bfc[0];
}

// ---------------------------------------------------------------------------
extern "C" void kernel_launch(void* const* d_in, const int* in_sizes, int n_in,
                              void* d_out, int out_size, void* d_ws, size_t ws_size,
                              hipStream_t stream) {
    const float* x    = (const float*)d_in[0];
    const float* Wih0 = (const float*)d_in[1];
    const float* Whh0 = (const float*)d_in[2];
    const float* bih0 = (const float*)d_in[3];
    const float* bhh0 = (const float*)d_in[4];
    const float* Wih1 = (const float*)d_in[5];
    const float* Whh1 = (const float*)d_in[6];
    const float* bih1 = (const float*)d_in[7];
    const float* bhh1 = (const float*)d_in[8];
    const float* Wfc  = (const float*)d_in[9];
    const float* bfc  = (const float*)d_in[10];
    float* out = (float*)d_out;

    char* ws = (char*)d_ws;
    size_t off = 0;
    auto carve = [&](size_t bytes) { void* p = ws + off; off += (bytes + 255) & ~(size_t)255; return p; };
    half_t* x16T   = (half_t*)carve((size_t)B_ * T_ * I_ * 2);              // 33.5 MB [t][B][512]
    half_t* h1seq  = (half_t*)carve((size_t)(T_ + 1) * B_ * H_ * 2);        // 67.4 MB [t][B][H]
    half_t* wp0    = (half_t*)carve((size_t)4096 * 1536 * 2);               // 12.6 MB
    half_t* wp1    = (half_t*)carve((size_t)4096 * 2048 * 2);               // 16.8 MB
    float*  bias0  = (float*)carve(4096 * 4);
    float*  bias1  = (float*)carve(4096 * 4);
    // states: h2a,h2b (fallback) + flags0(2KB) + flags1(2KB)
    char*   states = (char*)carve(2 * (size_t)B_ * H_ * 2 + 8192);
    if (off > ws_size) return;  // visible failure if ws too small

    half_t* h2a = (half_t*)states;
    half_t* h2b = h2a + B_ * H_;
    unsigned* flags0 = (unsigned*)(h2b + B_ * H_);
    unsigned* flags1 = flags0 + 512;

    // optional fast path: time-indexed h2seq (cached reads) if workspace allows
    half_t* h2seq = nullptr;
    if (off + (size_t)(T_ + 1) * B_ * H_ * 2 + 256 <= ws_size)
        h2seq = (half_t*)carve((size_t)(T_ + 1) * B_ * H_ * 2);             // +67.4 MB

    // prep
    k_convert_x<<<(B_ * T_ * I_ / 8 + 255) / 256, 256, 0, stream>>>(x, x16T, B_ * T_ * I_ / 8);
    k_pack_w<<<(4096 * 1536 + 255) / 256, 256, 0, stream>>>(Wih0, Whh0, wp0, 512, 1536);
    k_pack_w<<<(4096 * 2048 + 255) / 256, 256, 0, stream>>>(Wih1, Whh1, wp1, 1024, 2048);
    k_pack_bias<<<16, 256, 0, stream>>>(bih0, bhh0, bias0);
    k_pack_bias<<<16, 256, 0, stream>>>(bih1, bhh1, bias1);
    // per-launch zeroing (bench replays): h1seq[0], states(+flags), h2seq[0]
    k_zero<<<(B_ * H_ / 2 + 255) / 256, 256, 0, stream>>>((unsigned int*)h1seq, B_ * H_ / 2);
    {
        int n = (2 * B_ * H_ * 2 + 8192) / 4;
        k_zero<<<(n + 255) / 256, 256, 0, stream>>>((unsigned int*)states, n);
    }
    if (h2seq)
        k_zero<<<(B_ * H_ / 2 + 255) / 256, 256, 0, stream>>>((unsigned int*)h2seq, B_ * H_ / 2);

    // persistent, sequential layers, weights pinned in registers, flag sync
    if (h2seq) {
        lstm_persist<true><<<dim3(512), dim3(512), 0, stream>>>(
            x16T, h1seq, h2seq, (half_t*)0, wp0, wp1, bias0, bias1, flags0, flags1);
        k_fc<<<128, 64, 0, stream>>>(h2seq + (size_t)T_ * B_ * H_, Wfc, bfc, out);
    } else {
        lstm_persist<false><<<dim3(512), dim3(512), 0, stream>>>(
            x16T, h1seq, h2a, h2b, wp0, wp1, bias0, bias1, flags0, flags1);
        // t=255 (odd) writes h2a
        k_fc<<<128, 64, 0, stream>>>(h2a, Wfc, bfc, out);
    }
}

// Round 6
// 4332.822 us; speedup vs baseline: 1.6286x; 1.6286x over previous
//
#include <hip/hip_runtime.h>
#include <math.h>

typedef _Float16 half_t;
typedef _Float16 half8 __attribute__((ext_vector_type(8)));
typedef float f32x4 __attribute__((ext_vector_type(4)));
typedef unsigned long long u64;

#define B_ 128
#define T_ 256
#define I_ 512
#define H_ 1024

#define mfma16 __builtin_amdgcn_mfma_f32_16x16x32_f16

// ---------------------------------------------------------------------------
// prep: convert x fp32 -> fp16, TRANSPOSED to [t][row][k] (per-step slab = 128KB)
__global__ void k_convert_x(const float* __restrict__ x, half_t* __restrict__ x16, int n8) {
    int i = blockIdx.x * blockDim.x + threadIdx.x;
    if (i >= n8) return;
    const float4* xv = (const float4*)x;
    float4 a = xv[2 * i], b = xv[2 * i + 1];
    half8 o;
    o[0] = (half_t)a.x; o[1] = (half_t)a.y; o[2] = (half_t)a.z; o[3] = (half_t)a.w;
    o[4] = (half_t)b.x; o[5] = (half_t)b.y; o[6] = (half_t)b.z; o[7] = (half_t)b.w;
    int e = i * 8;
    int k = e & (I_ - 1);
    int t = (e >> 9) & (T_ - 1);
    int row = e >> 17;
    ((half8*)x16)[(((size_t)t * B_ + row) * I_ + k) >> 3] = o;
}

// prep: pack W_ih|W_hh (fp32, torch gate order i,f,g,o) into fp16 MFMA
// B-fragment order. Layout: [hgroup(128)][kb(Ktot/32)][ntile(2)][lane(64)][j(8)]
__global__ void k_pack_w(const float* __restrict__ Wih, const float* __restrict__ Whh,
                         half_t* __restrict__ out, int Kx, int Ktot) {
    int idx = blockIdx.x * blockDim.x + threadIdx.x;
    int total = 4096 * Ktot;
    if (idx >= total) return;
    int j = idx & 7;
    int lane = (idx >> 3) & 63;
    int nt = (idx >> 9) & 1;
    int rest = idx >> 10;
    int nkb = Ktot >> 5;
    int kb = rest % nkb;
    int hg = rest / nkb;
    int nl = nt * 16 + (lane & 15);
    int gate = nl >> 3, hoff = nl & 7;
    int row = gate * 1024 + hg * 8 + hoff;
    int k = kb * 32 + (lane >> 4) * 8 + j;
    float v = (k < Kx) ? Wih[(size_t)row * Kx + k] : Whh[(size_t)row * 1024 + (k - Kx)];
    out[idx] = (half_t)v;
}

// prep: bias packed to [hgroup*32 + gate*8 + hoff], b_ih + b_hh summed
__global__ void k_pack_bias(const float* __restrict__ bih, const float* __restrict__ bhh,
                            float* __restrict__ out) {
    int idx = blockIdx.x * blockDim.x + threadIdx.x;
    if (idx >= 4096) return;
    int hg = idx >> 5, c = idx & 31;
    int gate = c >> 3, hoff = c & 7;
    int row = gate * 1024 + hg * 8 + hoff;
    out[idx] = bih[row] + bhh[row];
}

__global__ void k_zero(unsigned int* __restrict__ p, int n) {
    int i = blockIdx.x * blockDim.x + threadIdx.x;
    if (i < n) p[i] = 0u;
}

// ---------------------------------------------------------------------------
// system-scope primitives (validated r2-r5: write-through store + fresh-address
// cached load is coherent across XCDs; sysld for reused addresses)
__device__ __forceinline__ u64 sysld64(const half_t* p) {
    return __hip_atomic_load((const u64*)p, __ATOMIC_RELAXED, __HIP_MEMORY_SCOPE_SYSTEM);
}
// 16B write-through store (single transaction, L2-bypassing, MALL-visible)
__device__ __forceinline__ void sysst128(half_t* p, half8 v) {
    asm volatile("global_store_dwordx4 %0, %1, off sc0 sc1"
                 :: "v"(p), "v"(v) : "memory");
}
union H8U { half8 h; u64 u[2]; };

// Block-wide wait: ONLY wave 0 polls (128 flags, 2/lane, throttled);
// the hardware barrier releases the other 7 waves. 512 poll streams total.
__device__ __forceinline__ void block_wait_all(const unsigned* f, unsigned tgt) {
    if (threadIdx.x < 64) {
        int lane = threadIdx.x;
        int gd = 0;
        for (;;) {
            unsigned a = __hip_atomic_load(f + lane, __ATOMIC_RELAXED,
                                           __HIP_MEMORY_SCOPE_SYSTEM);
            unsigned b = __hip_atomic_load(f + 64 + lane, __ATOMIC_RELAXED,
                                           __HIP_MEMORY_SCOPE_SYSTEM);
            if (__all((int)(a >= tgt && b >= tgt))) break;
            __builtin_amdgcn_s_sleep(4);
            if (++gd > (1 << 15)) break;  // failsafe: visible fail, not a hang
        }
    }
    __syncthreads();
    asm volatile("" ::: "memory");
}

// ---------------------------------------------------------------------------
// One layer, persistent. Block = 512 thr = 8 waves. Block tile: 32 rows (rg)
// x 32 gate-cols (cg == hgroup). Weights pinned in registers.
// Per step: phase1 (non-recurrent K) -> block wait on producer flags ->
// phase2 (recurrent K) -> LDS reduce -> elementwise -> h to LDS hstage ->
// wave0: 32x 16B system stores + vmcnt(0) + flag store. No trailing barrier:
// waves 1-7 run ahead into next step's phase1 while wave0 drains.
template <int KX, bool LAY1, bool H2SEQ>
__device__ void run_layer(const half_t* __restrict__ srcX,
                          half_t* hA, half_t* hB,
                          const half_t* __restrict__ Wp, const float* __restrict__ biasp,
                          unsigned* flagsPre, unsigned* flagsOwn,   // [rg*128 + cg]
                          int rg, int cg, float* gacc, half_t* hstage)
{
    constexpr int KTOT = KX + 1024;
    constexpr int NKB  = KTOT >> 5;   // 48 / 64
    constexpr int NI_X = KX >> 8;     // 2 / 4 phase-1 kbs per wave
    constexpr int NI_H = 4;           // phase-2 kbs per wave
    constexpr int NI   = NI_X + NI_H; // 6 / 8

    const int tid = threadIdx.x;
    const int ks = tid >> 6, lane = tid & 63;
    const int q = lane >> 4, ml = lane & 15;
    const int hg = cg;
    const int r0 = rg * 32;

    // ---- one-time weight preload into registers, pinned (no remat/sink) ----
    half8 Breg[NI][2];
    {
        const half8* Wp8 = (const half8*)Wp;
        size_t base = (size_t)hg * NKB * 128 + lane;
#pragma unroll
        for (int i = 0; i < NI; ++i) {
            int kb = (i < NI_X) ? (NI_X * ks + i) : (KX / 32 + 4 * ks + (i - NI_X));
            Breg[i][0] = Wp8[base + (size_t)kb * 128];
            Breg[i][1] = Wp8[base + (size_t)kb * 128 + 64];
        }
#pragma unroll
        for (int i = 0; i < NI; ++i)
            asm volatile("" : "+v"(Breg[i][0]), "+v"(Breg[i][1]));
    }

    const int erow = tid >> 3, ehoff = tid & 7;  // elementwise id (tid<256)
    float bi = 0.f, bf = 0.f, bgc = 0.f, bo = 0.f;
    if (tid < 256) {
        bi  = biasp[hg * 32 + 0 + ehoff];
        bf  = biasp[hg * 32 + 8 + ehoff];
        bgc = biasp[hg * 32 + 16 + ehoff];
        bo  = biasp[hg * 32 + 24 + ehoff];
    }
    float c_reg = 0.f;

    const unsigned* fpre = flagsPre + rg * 128;
    const unsigned* fown = flagsOwn + rg * 128;
    unsigned* myFlag = flagsOwn + rg * 128 + cg;

    for (int t = 0; t < T_; ++t) {
        f32x4 acc[2][2];
        acc[0][0] = (f32x4)0.f; acc[0][1] = (f32x4)0.f;
        acc[1][0] = (f32x4)0.f; acc[1][1] = (f32x4)0.f;

        // ---- phase 1: non-recurrent operand ----
        if constexpr (LAY1) block_wait_all(fpre, (unsigned)(t + 1));  // h1seq[t+1]
        const int t1 = LAY1 ? (t + 1) : t;
#pragma unroll
        for (int i = 0; i < NI_X; ++i) {
            int kg = 32 * (NI_X * ks + i) + q * 8;
#pragma unroll
            for (int rt = 0; rt < 2; ++rt) {
                int grow = r0 + rt * 16 + ml;
                half8 a = *(const half8*)(srcX + ((size_t)t1 * B_ + grow) * KX + kg);
                acc[rt][0] = mfma16(a, Breg[i][0], acc[rt][0], 0, 0, 0);
                acc[rt][1] = mfma16(a, Breg[i][1], acc[rt][1], 0, 0, 0);
            }
        }
        // ---- phase 2: recurrent operand ----
        if (t > 0) block_wait_all(fown, (unsigned)t);
        const half_t* hp;
        if constexpr (!LAY1 || H2SEQ) hp = hA + (size_t)t * B_ * H_;
        else                          hp = (t & 1) ? hB : hA;
#pragma unroll
        for (int j = 0; j < NI_H; ++j) {
            int i = NI_X + j;
            int kh = 32 * (4 * ks + j) + q * 8;   // h-unit index in [0,1024)
#pragma unroll
            for (int rt = 0; rt < 2; ++rt) {
                int grow = r0 + rt * 16 + ml;
                half8 a;
                if constexpr (LAY1 && !H2SEQ) {
                    H8U u; const half_t* p = hp + (size_t)grow * H_ + kh;
                    u.u[0] = sysld64(p); u.u[1] = sysld64(p + 4);
                    a = u.h;
                } else {
                    a = *(const half8*)(hp + (size_t)grow * H_ + kh);
                }
                acc[rt][0] = mfma16(a, Breg[i][0], acc[rt][0], 0, 0, 0);
                acc[rt][1] = mfma16(a, Breg[i][1], acc[rt][1], 0, 0, 0);
            }
        }
        // ---- partials -> LDS (<=2-way conflicts) ----
#pragma unroll
        for (int rt = 0; rt < 2; ++rt)
#pragma unroll
            for (int ct = 0; ct < 2; ++ct)
#pragma unroll
                for (int r = 0; r < 4; ++r) {
                    int rl = rt * 16 + q * 4 + r;
                    int cl = ct * 16 + ml;
                    gacc[(ks * 32 + rl) * 32 + (cl ^ ((rl & 7) << 2))] = acc[rt][ct][r];
                }
        __syncthreads();
        // ---- reduce 8 K-slices + elementwise (tid<256), h -> LDS hstage ----
        if (tid < 256) {
            int swz = (erow & 7) << 2;
            float pi = 0.f, pf = 0.f, pg = 0.f, po = 0.f;
#pragma unroll
            for (int z = 0; z < 8; ++z) {
                const float* g = &gacc[(z * 32 + erow) * 32];
                pi += g[(0 + ehoff) ^ swz];
                pf += g[(8 + ehoff) ^ swz];
                pg += g[(16 + ehoff) ^ swz];
                po += g[(24 + ehoff) ^ swz];
            }
            pi += bi; pf += bf; pg += bgc; po += bo;
            float si = 1.f / (1.f + __expf(-pi));
            float sf = 1.f / (1.f + __expf(-pf));
            float so = 1.f / (1.f + __expf(-po));
            float tg = 1.f - 2.f / (__expf(2.f * pg) + 1.f);
            c_reg = sf * c_reg + si * tg;
            float th = 1.f - 2.f / (__expf(2.f * c_reg) + 1.f);
            float hn = so * th;
            hstage[erow * 8 + ehoff] = (half_t)hn;
        }
        __syncthreads();
        // ---- publish: wave0 only. 32 x 16B system stores, then flag ----
        if (tid < 32) {
            half8 hv = *(const half8*)(hstage + tid * 8);
            half_t* dst;
            if constexpr (!LAY1 || H2SEQ)
                dst = hA + ((size_t)(t + 1) * B_ + (r0 + tid)) * H_ + hg * 8;
            else
                dst = ((t & 1) ? hA : hB) + (size_t)(r0 + tid) * H_ + hg * 8;
            sysst128(dst, hv);
        }
        if (tid == 0) {
            asm volatile("s_waitcnt vmcnt(0)" ::: "memory");  // drain the 32 stores
            __hip_atomic_store(myFlag, (unsigned)(t + 1),
                               __ATOMIC_RELAXED, __HIP_MEMORY_SCOPE_SYSTEM);
        }
        // no trailing barrier: waves 1-7 proceed into next step's phase 1;
        // wave0 rejoins at the next block_wait_all / gacc barrier.
    }
}

// ---------------------------------------------------------------------------
// 512 blocks x 512 thr, 2 blocks/CU. Sequential layers per block.
// rg = bid&3 keeps each rg-group on a stable XCD subset (locality only).
template <bool H2SEQ>
__launch_bounds__(512, 4)
__global__ void lstm_persist(const half_t* __restrict__ x16T, half_t* h1seq,
                             half_t* h2A, half_t* h2B,
                             const half_t* __restrict__ wp0, const half_t* __restrict__ wp1,
                             const float* __restrict__ bias0, const float* __restrict__ bias1,
                             unsigned* __restrict__ flags0, unsigned* __restrict__ flags1)
{
    __shared__ float gacc[8 * 32 * 32];   // 32 KB
    __shared__ half_t hstage[32 * 8];     // 512 B
    int bid = blockIdx.x;
    int rg = bid & 3;
    int cg = bid >> 2;

    run_layer<512, false, true>(x16T, h1seq, (half_t*)0, wp0, bias0,
                                flags0, flags0, rg, cg, gacc, hstage);
    run_layer<1024, true, H2SEQ>(h1seq, h2A, h2B, wp1, bias1,
                                 flags0, flags1, rg, cg, gacc, hstage);
}

// final FC: out[m] = sum_k h[m][k] * Wfc[k] + bfc  (NC=1)
__global__ void k_fc(const half_t* __restrict__ h, const float* __restrict__ Wfc,
                     const float* __restrict__ bfc, float* __restrict__ out) {
    int m = blockIdx.x, lane = threadIdx.x;
    float s = 0.f;
    for (int k = lane; k < H_; k += 64) s += (float)h[m * H_ + k] * Wfc[k];
#pragma unroll
    for (int o = 32; o; o >>= 1) s += __shfl_down(s, o, 64);
    if (lane == 0) out[m] = s + bfc[0];
}

// ---------------------------------------------------------------------------
extern "C" void kernel_launch(void* const* d_in, const int* in_sizes, int n_in,
                              void* d_out, int out_size, void* d_ws, size_t ws_size,
                              hipStream_t stream) {
    const float* x    = (const float*)d_in[0];
    const float* Wih0 = (const float*)d_in[1];
    const float* Whh0 = (const float*)d_in[2];
    const float* bih0 = (const float*)d_in[3];
    const float* bhh0 = (const float*)d_in[4];
    const float* Wih1 = (const float*)d_in[5];
    const float* Whh1 = (const float*)d_in[6];
    const float* bih1 = (const float*)d_in[7];
    const float* bhh1 = (const float*)d_in[8];
    const float* Wfc  = (const float*)d_in[9];
    const float* bfc  = (const float*)d_in[10];
    float* out = (float*)d_out;

    char* ws = (char*)d_ws;
    size_t off = 0;
    auto carve = [&](size_t bytes) { void* p = ws + off; off += (bytes + 255) & ~(size_t)255; return p; };
    half_t* x16T   = (half_t*)carve((size_t)B_ * T_ * I_ * 2);              // 33.5 MB [t][B][512]
    half_t* h1seq  = (half_t*)carve((size_t)(T_ + 1) * B_ * H_ * 2);        // 67.4 MB [t][B][H]
    half_t* wp0    = (half_t*)carve((size_t)4096 * 1536 * 2);               // 12.6 MB
    half_t* wp1    = (half_t*)carve((size_t)4096 * 2048 * 2);               // 16.8 MB
    float*  bias0  = (float*)carve(4096 * 4);
    float*  bias1  = (float*)carve(4096 * 4);
    // states: h2a,h2b (fallback) + flags0(2KB) + flags1(2KB)
    char*   states = (char*)carve(2 * (size_t)B_ * H_ * 2 + 8192);
    if (off > ws_size) return;  // visible failure if ws too small

    half_t* h2a = (half_t*)states;
    half_t* h2b = h2a + B_ * H_;
    unsigned* flags0 = (unsigned*)(h2b + B_ * H_);
    unsigned* flags1 = flags0 + 512;

    // optional fast path: time-indexed h2seq (cached reads) if workspace allows
    half_t* h2seq = nullptr;
    if (off + (size_t)(T_ + 1) * B_ * H_ * 2 + 256 <= ws_size)
        h2seq = (half_t*)carve((size_t)(T_ + 1) * B_ * H_ * 2);             // +67.4 MB

    // prep
    k_convert_x<<<(B_ * T_ * I_ / 8 + 255) / 256, 256, 0, stream>>>(x, x16T, B_ * T_ * I_ / 8);
    k_pack_w<<<(4096 * 1536 + 255) / 256, 256, 0, stream>>>(Wih0, Whh0, wp0, 512, 1536);
    k_pack_w<<<(4096 * 2048 + 255) / 256, 256, 0, stream>>>(Wih1, Whh1, wp1, 1024, 2048);
    k_pack_bias<<<16, 256, 0, stream>>>(bih0, bhh0, bias0);
    k_pack_bias<<<16, 256, 0, stream>>>(bih1, bhh1, bias1);
    // per-launch zeroing (bench replays): h1seq[0], states(+flags), h2seq[0]
    k_zero<<<(B_ * H_ / 2 + 255) / 256, 256, 0, stream>>>((unsigned int*)h1seq, B_ * H_ / 2);
    {
        int n = (2 * B_ * H_ * 2 + 8192) / 4;
        k_zero<<<(n + 255) / 256, 256, 0, stream>>>((unsigned int*)states, n);
    }
    if (h2seq)
        k_zero<<<(B_ * H_ / 2 + 255) / 256, 256, 0, stream>>>((unsigned int*)h2seq, B_ * H_ / 2);

    // persistent, sequential layers, weights pinned in registers, flag sync
    if (h2seq) {
        lstm_persist<true><<<dim3(512), dim3(512), 0, stream>>>(
            x16T, h1seq, h2seq, (half_t*)0, wp0, wp1, bias0, bias1, flags0, flags1);
        k_fc<<<128, 64, 0, stream>>>(h2seq + (size_t)T_ * B_ * H_, Wfc, bfc, out);
    } else {
        lstm_persist<false><<<dim3(512), dim3(512), 0, stream>>>(
            x16T, h1seq, h2a, h2b, wp0, wp1, bias0, bias1, flags0, flags1);
        // t=255 (odd) writes h2a
        k_fc<<<128, 64, 0, stream>>>(h2a, Wfc, bfc, out);
    }
}